// Round 3
// baseline (930.825 us; speedup 1.0000x reference)
//
#include <hip/hip_runtime.h>
#include <hip/hip_bf16.h>

#define T_TASKS 8
#define B_ROWS 4096
#define PADROWS 4224      // +128 so partial-tile A loads stay in-bounds
#define BM 128
#define BN 128
#define BK 64
#define MAXTILES 40       // sum over tasks of ceil(cnt/BM) <= T + B/BM = 40

typedef __attribute__((ext_vector_type(4))) float f32x4;
typedef __attribute__((ext_vector_type(8))) short bf16x8;

#define GLOAD_LDS16(g, l) __builtin_amdgcn_global_load_lds( \
    (const __attribute__((address_space(1))) void*)(g), \
    (__attribute__((address_space(3))) void*)(l), 16, 0, 0)

__device__ __forceinline__ unsigned short f32_to_bf16(float f) {
    union { float f; unsigned int u; } v; v.f = f;
    unsigned int r = v.u + 0x7FFF + ((v.u >> 16) & 1);  // RNE
    return (unsigned short)(r >> 16);
}

__device__ __forceinline__ unsigned int pack2_bf16(float lo, float hi) {
    __hip_bfloat162 h = __float22bfloat162_rn(make_float2(lo, hi));  // lo -> low 16 bits
    union { __hip_bfloat162 h; unsigned int u; } c; c.h = h;
    return c.u;
}

// ---------------- setup: counting sort by task + tile table ----------------
__global__ void setup_kernel(const int* __restrict__ task, int* __restrict__ perm,
                             int* __restrict__ offs, int* __restrict__ table) {
    __shared__ int cnt[T_TASKS];
    __shared__ int cur[T_TASKS];
    int tid = threadIdx.x;
    if (tid < T_TASKS) cnt[tid] = 0;
    __syncthreads();
    for (int b = tid; b < B_ROWS; b += blockDim.x)
        atomicAdd(&cnt[task[b]], 1);
    __syncthreads();
    if (tid == 0) {
        int o = 0;
        for (int t = 0; t < T_TASKS; ++t) { offs[t] = o; cur[t] = o; o += cnt[t]; }
        offs[T_TASKS] = o;
        int s = 0;
        for (int t = 0; t < T_TASKS; ++t) {
            int nt = (cnt[t] + BM - 1) / BM;
            for (int j = 0; j < nt; ++j) table[s++] = (t << 16) | j;
        }
        for (; s < MAXTILES; ++s) table[s] = -1;
    }
    __syncthreads();
    for (int b = tid; b < B_ROWS; b += blockDim.x) {
        int t = task[b];
        int pos = atomicAdd(&cur[t], 1);
        perm[pos] = b;
    }
}

// ---------------- permute + cast x -> bf16 ----------------
__global__ void permute_cast_kernel(const float* __restrict__ x, const int* __restrict__ perm,
                                    unsigned short* __restrict__ xp) {
    int rowp = blockIdx.x;
    int src = perm[rowp];
    const float4* xin = reinterpret_cast<const float4*>(x + (size_t)src * 1024);
    unsigned short* dst = xp + (size_t)rowp * 1024;
    int c4 = threadIdx.x;
    float4 v = xin[c4];
    ushort4 o;
    o.x = f32_to_bf16(v.x); o.y = f32_to_bf16(v.y);
    o.z = f32_to_bf16(v.z); o.w = f32_to_bf16(v.w);
    *reinterpret_cast<ushort4*>(dst + c4 * 4) = o;
}

// ---------------- VAE reparameterization ----------------
__global__ void vae_kernel(const float* __restrict__ scat, const float* __restrict__ eps,
                           const int* __restrict__ perm, unsigned short* __restrict__ z) {
    int rowp = blockIdx.x;
    int c = threadIdx.x;
    int src = perm[rowp];
    float mu = scat[(size_t)rowp * 512 + c];
    float ls = scat[(size_t)rowp * 512 + 256 + c];
    float e  = eps[(size_t)src * 256 + c];
    z[(size_t)rowp * 256 + c] = f32_to_bf16(mu + __expf(ls) * e);
}

// ---------------- grouped GEMM, f32 [K][N] weights consumed directly ----------------
// A: bf16 [rowp][K] grouped by task (padded rows). W: f32 [t][K][N]. bias: f32 [t][N].
// Double-buffered LDS, BK=64. A staged via global_load_lds with source-swizzled
// addresses (XOR chunk^(row&7)); B reg-staged: f32 loads -> cvt_pk bf16 -> swizzled
// ds_write_b128 into [n][k] layout. All LDS frag reads use the matching XOR -> ~conflict-free.
// MODE 0: relu -> bf16 store; MODE 1: f32 store; MODE 2: sigmoid -> f32 scatter via perm
template<int MODE>
__global__ __launch_bounds__(256, 2)
void gemm3_kernel(const unsigned short* __restrict__ A,
                  const float* __restrict__ W,
                  const float* __restrict__ bias, void* __restrict__ dst,
                  const int* __restrict__ offs, const int* __restrict__ table,
                  const int* __restrict__ perm,
                  int K, int N, int ldd, int Btot)
{
    int t, mtile, off, cnt;
    if (table != nullptr) {
        int v = table[blockIdx.x];
        if (v < 0) return;
        t = v >> 16; mtile = v & 0xFFFF;
        off = offs[t]; cnt = offs[t + 1] - off;
    } else {
        t = 0; mtile = blockIdx.x; off = 0; cnt = Btot;
    }
    const int n0 = blockIdx.y * BN;
    const float* Wt = W + (size_t)t * K * N;

    __shared__ unsigned short As[2][BM * BK];   // 16 KB each
    __shared__ unsigned short Bs[2][BN * BK];   // 16 KB each

    const int tid  = threadIdx.x;
    const int lane = tid & 63;
    const int wave = tid >> 6;
    const int wr = wave >> 1, wc = wave & 1;

    // A staging geometry: 16 lines of 1 KiB; wave w owns lines w*4..w*4+3.
    // Within a line: lane -> row (lane>>3), 16B-chunk (lane&7), source chunk XOR (row&7).
    const int arow   = lane >> 3;                      // 0..7 (also == row&7)
    const int achunk = ((lane & 7) ^ arow) * 8;        // ushort offset in 64-elem k-slab
    const size_t abase = (size_t)(off + mtile * BM);

    // B staging geometry: thread -> k-group (tid>>5)*8.. , n pair base 2*(tid&31)
    const int t31 = tid & 31;
    const int kg  = tid >> 5;

    float2 breg[8][2];

    auto stage_a = [&](int buf, int k0) {
        #pragma unroll
        for (int jj = 0; jj < 4; ++jj) {
            int j = wave * 4 + jj;
            const unsigned short* src = A + (abase + (size_t)(j * 8 + arow)) * K + k0 + achunk;
            GLOAD_LDS16(src, &As[buf][j * 512]);
        }
    };
    auto load_b = [&](int k0) {
        #pragma unroll
        for (int r = 0; r < 8; ++r) {
            const float* rp = Wt + (size_t)(k0 + kg * 8 + r) * N + n0 + 2 * t31;
            breg[r][0] = *reinterpret_cast<const float2*>(rp);
            breg[r][1] = *reinterpret_cast<const float2*>(rp + 64);
        }
    };
    auto write_b = [&](int buf) {
        #pragma unroll
        for (int j = 0; j < 2; ++j) {
            #pragma unroll
            for (int e = 0; e < 2; ++e) {
                int nl = 2 * t31 + 64 * j + e;
                uint4 wv;
                wv.x = pack2_bf16(e ? breg[0][j].y : breg[0][j].x, e ? breg[1][j].y : breg[1][j].x);
                wv.y = pack2_bf16(e ? breg[2][j].y : breg[2][j].x, e ? breg[3][j].y : breg[3][j].x);
                wv.z = pack2_bf16(e ? breg[4][j].y : breg[4][j].x, e ? breg[5][j].y : breg[5][j].x);
                wv.w = pack2_bf16(e ? breg[6][j].y : breg[6][j].x, e ? breg[7][j].y : breg[7][j].x);
                *reinterpret_cast<uint4*>(&Bs[buf][nl * 64 + ((kg * 8) ^ ((nl & 7) << 3))]) = wv;
            }
        }
    };

    f32x4 acc[4][4];
    #pragma unroll
    for (int m = 0; m < 4; ++m)
        #pragma unroll
        for (int n = 0; n < 4; ++n)
            acc[m][n] = (f32x4){0.f, 0.f, 0.f, 0.f};

    auto compute = [&](int buf) {
        #pragma unroll
        for (int kh = 0; kh < 2; ++kh) {
            bf16x8 af[4], bfr[4];
            #pragma unroll
            for (int m = 0; m < 4; ++m) {
                int rf = wr * 64 + m * 16 + (lane & 15);
                af[m] = *reinterpret_cast<const bf16x8*>(
                    &As[buf][rf * 64 + ((kh * 32 + (lane >> 4) * 8) ^ ((rf & 7) << 3))]);
            }
            #pragma unroll
            for (int n = 0; n < 4; ++n) {
                int nf = wc * 64 + n * 16 + (lane & 15);
                bfr[n] = *reinterpret_cast<const bf16x8*>(
                    &Bs[buf][nf * 64 + ((kh * 32 + (lane >> 4) * 8) ^ ((nf & 7) << 3))]);
            }
            #pragma unroll
            for (int m = 0; m < 4; ++m)
                #pragma unroll
                for (int n = 0; n < 4; ++n)
                    acc[m][n] = __builtin_amdgcn_mfma_f32_16x16x32_bf16(af[m], bfr[n], acc[m][n], 0, 0, 0);
        }
    };

    // ---- prologue ----
    const int nsteps = K / BK;
    load_b(0);
    stage_a(0, 0);
    write_b(0);          // compiler inserts vmcnt wait for breg deps
    __syncthreads();     // drains global_load_lds + ds_writes

    int cur = 0;
    for (int s = 0; s < nsteps; ++s) {
        if (s + 1 < nsteps) {
            stage_a(cur ^ 1, (s + 1) * BK);   // async -> LDS[next]
            load_b((s + 1) * BK);             // -> regs, latency hidden under compute
        }
        compute(cur);
        if (s + 1 < nsteps) write_b(cur ^ 1);
        __syncthreads();
        cur ^= 1;
    }

    // ---- epilogue ----
    const float* bt = bias + (size_t)t * N;
    #pragma unroll
    for (int n = 0; n < 4; ++n) {
        int col = n0 + wc * 64 + n * 16 + (lane & 15);
        float bv = bt[col];
        #pragma unroll
        for (int m = 0; m < 4; ++m) {
            int rbase = mtile * BM + wr * 64 + m * 16 + ((lane >> 4) << 2);
            #pragma unroll
            for (int j = 0; j < 4; ++j) {
                int local = rbase + j;
                if (local >= cnt) continue;
                float v = acc[m][n][j] + bv;
                if (MODE == 0) {
                    ((unsigned short*)dst)[(size_t)(off + local) * ldd + col] =
                        f32_to_bf16(fmaxf(v, 0.f));
                } else if (MODE == 1) {
                    ((float*)dst)[(size_t)(off + local) * ldd + col] = v;
                } else {
                    int grow = perm[off + local];
                    ((float*)dst)[(size_t)grow * ldd + col] = 1.f / (1.f + __expf(-v));
                }
            }
        }
    }
}

extern "C" void kernel_launch(void* const* d_in, const int* in_sizes, int n_in,
                              void* d_out, int out_size, void* d_ws, size_t ws_size,
                              hipStream_t stream) {
    const float* x      = (const float*)d_in[0];
    const int*   task   = (const int*)d_in[1];
    const float* eps    = (const float*)d_in[2];
    const float* enc_W1 = (const float*)d_in[3];
    const float* enc_b1 = (const float*)d_in[4];
    const float* enc_W2 = (const float*)d_in[5];
    const float* enc_b2 = (const float*)d_in[6];
    const float* enc_W3 = (const float*)d_in[7];
    const float* enc_b3 = (const float*)d_in[8];
    const float* enc_W4 = (const float*)d_in[9];
    const float* enc_b4 = (const float*)d_in[10];
    const float* ds_W1  = (const float*)d_in[11];
    const float* ds_b1  = (const float*)d_in[12];
    const float* ds_W2  = (const float*)d_in[13];
    const float* ds_b2  = (const float*)d_in[14];
    const float* hd_W1  = (const float*)d_in[15];
    const float* hd_b1  = (const float*)d_in[16];
    const float* hd_W2  = (const float*)d_in[17];
    const float* hd_b2  = (const float*)d_in[18];
    float* out = (float*)d_out;

    // ---- workspace layout (~46 MB) ----
    char* ws = (char*)d_ws;
    int* perm  = (int*)ws;
    int* offs  = (int*)(ws + 16384);
    int* table = (int*)(ws + 16384 + 256);
    char* p = ws + 32768;
    unsigned short* xp = (unsigned short*)p; p += (size_t)PADROWS * 1024 * 2;
    unsigned short* h1 = (unsigned short*)p; p += (size_t)PADROWS * 2048 * 2;
    unsigned short* h2 = (unsigned short*)p; p += (size_t)PADROWS * 2048 * 2;
    unsigned short* zb = (unsigned short*)p; p += (size_t)PADROWS * 256 * 2;
    float* scat = out;   // reuse d_out as 8 MB scat scratch; fully overwritten later

    setup_kernel<<<1, 1024, 0, stream>>>(task, perm, offs, table);
    permute_cast_kernel<<<B_ROWS, 256, 0, stream>>>(x, perm, xp);

    // encoder (grouped by task)
    gemm3_kernel<0><<<dim3(MAXTILES, 16), 256, 0, stream>>>(xp, enc_W1, enc_b1, h1, offs, table, nullptr, 1024, 2048, 2048, B_ROWS);
    gemm3_kernel<0><<<dim3(MAXTILES, 16), 256, 0, stream>>>(h1, enc_W2, enc_b2, h2, offs, table, nullptr, 2048, 2048, 2048, B_ROWS);
    gemm3_kernel<0><<<dim3(MAXTILES, 16), 256, 0, stream>>>(h2, enc_W3, enc_b3, h1, offs, table, nullptr, 2048, 2048, 2048, B_ROWS);
    gemm3_kernel<1><<<dim3(MAXTILES, 4), 256, 0, stream>>>(h1, enc_W4, enc_b4, scat, offs, table, nullptr, 2048, 512, 512, B_ROWS);

    vae_kernel<<<B_ROWS, 256, 0, stream>>>(scat, eps, perm, zb);

    // decoder shared layers (ungrouped: t=0, all rows)
    gemm3_kernel<0><<<dim3(32, 16), 256, 0, stream>>>(zb, ds_W1, ds_b1, h2, nullptr, nullptr, nullptr, 256, 2048, 2048, B_ROWS);
    gemm3_kernel<0><<<dim3(32, 16), 256, 0, stream>>>(h2, ds_W2, ds_b2, h1, nullptr, nullptr, nullptr, 2048, 2048, 2048, B_ROWS);

    // heads (grouped)
    gemm3_kernel<0><<<dim3(MAXTILES, 16), 256, 0, stream>>>(h1, hd_W1, hd_b1, h2, offs, table, nullptr, 2048, 2048, 2048, B_ROWS);
    gemm3_kernel<2><<<dim3(MAXTILES, 8), 256, 0, stream>>>(h2, hd_W2, hd_b2, out, offs, table, perm, 2048, 1024, 1024, B_ROWS);
}

// Round 4
// 663.701 us; speedup vs baseline: 1.4025x; 1.4025x over previous
//
#include <hip/hip_runtime.h>
#include <hip/hip_bf16.h>

#define T_TASKS 8
#define B_ROWS 4096
#define PADROWS 4224      // +128 so partial-tile A loads stay in-bounds
#define BM 128
#define BN 128
#define BK 32
#define MAXTILES 40       // sum over tasks of ceil(cnt/BM) <= T + B/BM = 40

typedef __attribute__((ext_vector_type(4))) float f32x4;
typedef __attribute__((ext_vector_type(8))) short bf16x8;

#define GLOAD_LDS16(g, l) __builtin_amdgcn_global_load_lds( \
    (const __attribute__((address_space(1))) void*)(g), \
    (__attribute__((address_space(3))) void*)(l), 16, 0, 0)

struct TP { const float* src; unsigned short* dst; int K; int N; int ntiles; };

__device__ __forceinline__ unsigned short f32_to_bf16(float f) {
    union { float f; unsigned int u; } v; v.f = f;
    unsigned int r = v.u + 0x7FFF + ((v.u >> 16) & 1);  // RNE
    return (unsigned short)(r >> 16);
}

// ---------------- setup: counting sort by task + tile table ----------------
__global__ void setup_kernel(const int* __restrict__ task, int* __restrict__ perm,
                             int* __restrict__ offs, int* __restrict__ table) {
    __shared__ int cnt[T_TASKS];
    __shared__ int cur[T_TASKS];
    int tid = threadIdx.x;
    if (tid < T_TASKS) cnt[tid] = 0;
    __syncthreads();
    for (int b = tid; b < B_ROWS; b += blockDim.x)
        atomicAdd(&cnt[task[b]], 1);
    __syncthreads();
    if (tid == 0) {
        int o = 0;
        for (int t = 0; t < T_TASKS; ++t) { offs[t] = o; cur[t] = o; o += cnt[t]; }
        offs[T_TASKS] = o;
        int s = 0;
        for (int t = 0; t < T_TASKS; ++t) {
            int nt = (cnt[t] + BM - 1) / BM;
            for (int j = 0; j < nt; ++j) table[s++] = (t << 16) | j;
        }
        for (; s < MAXTILES; ++s) table[s] = -1;
    }
    __syncthreads();
    for (int b = tid; b < B_ROWS; b += blockDim.x) {
        int t = task[b];
        int pos = atomicAdd(&cur[t], 1);
        perm[pos] = b;
    }
}

// ---------------- permute + cast x -> bf16 ----------------
__global__ void permute_cast_kernel(const float* __restrict__ x, const int* __restrict__ perm,
                                    unsigned short* __restrict__ xp) {
    int rowp = blockIdx.x;
    int src = perm[rowp];
    const float4* xin = reinterpret_cast<const float4*>(x + (size_t)src * 1024);
    unsigned short* dst = xp + (size_t)rowp * 1024;
    int c4 = threadIdx.x;
    float4 v = xin[c4];
    ushort4 o;
    o.x = f32_to_bf16(v.x); o.y = f32_to_bf16(v.y);
    o.z = f32_to_bf16(v.z); o.w = f32_to_bf16(v.w);
    *reinterpret_cast<ushort4*>(dst + c4 * 4) = o;
}

// ---------------- VAE reparameterization ----------------
__global__ void vae_kernel(const float* __restrict__ scat, const float* __restrict__ eps,
                           const int* __restrict__ perm, unsigned short* __restrict__ z) {
    int rowp = blockIdx.x;
    int c = threadIdx.x;
    int src = perm[rowp];
    float mu = scat[(size_t)rowp * 512 + c];
    float ls = scat[(size_t)rowp * 512 + 256 + c];
    float e  = eps[(size_t)src * 256 + c];
    z[(size_t)rowp * 256 + c] = f32_to_bf16(mu + __expf(ls) * e);
}

// ---------------- standalone weight transpose (enc_W1 only) ----------------
// f32 [K][N] -> bf16 [N][K]. grid (K/64, N/64, T), block 256.
__global__ __launch_bounds__(256)
void transpose_cast_kernel(const float* __restrict__ W, unsigned short* __restrict__ Wt,
                           int K, int N) {
    const size_t toff = (size_t)blockIdx.z * K * N;
    const float* Ws = W + toff;
    unsigned short* Wd = Wt + toff;
    const int k0 = blockIdx.x * 64;
    const int n0 = blockIdx.y * 64;
    __shared__ unsigned short Tt[64 * 64];
    const int tid = threadIdx.x;
    const int n = tid & 63;
    const int kq = tid >> 6;
    #pragma unroll
    for (int i = 0; i < 4; ++i) {
        int kk = kq * 16 + i * 4;
        const float* p = Ws + (size_t)(k0 + kk) * N + n0 + n;
        float v0 = p[0];
        float v1 = p[(size_t)N];
        float v2 = p[(size_t)2 * N];
        float v3 = p[(size_t)3 * N];
        unsigned int lo = (unsigned int)f32_to_bf16(v0) | ((unsigned int)f32_to_bf16(v1) << 16);
        unsigned int hi = (unsigned int)f32_to_bf16(v2) | ((unsigned int)f32_to_bf16(v3) << 16);
        int c = (kk >> 2) ^ (n & 15);
        *reinterpret_cast<uint2*>(Tt + n * 64 + c * 4) = make_uint2(lo, hi);
    }
    __syncthreads();
    #pragma unroll
    for (int it = 0; it < 2; ++it) {
        int c  = it * 256 + tid;
        int nn = c >> 3;
        int cg = c & 7;
        int c1 = (cg * 2) ^ (nn & 15);
        int c2 = (cg * 2 + 1) ^ (nn & 15);
        uint2 a = *reinterpret_cast<const uint2*>(Tt + nn * 64 + c1 * 4);
        uint2 b = *reinterpret_cast<const uint2*>(Tt + nn * 64 + c2 * 4);
        uint4 o = make_uint4(a.x, a.y, b.x, b.y);
        *reinterpret_cast<uint4*>(Wd + (size_t)(n0 + nn) * K + k0 + cg * 8) = o;
    }
}

// ---------------- fused grouped GEMM + transpose-role blocks ----------------
// GEMM (blockIdx.x < GX): A bf16 [rowp][K] grouped; Wt bf16 [t][N][K]; bias f32 [t][N].
//   2-deep pipeline: stage(next) via global_load_lds BEFORE compute(cur); 1 barrier/step.
//   Matched XOR swizzle: source chunk ^= (row&3) at stage, same XOR at frag read.
// Transpose (blockIdx.x >= GX): up to two weight tensors, 64x64 tiles, flattened id.
// MODE 0: relu -> bf16; MODE 1: f32 store; MODE 2: sigmoid -> f32 scatter via perm
template<int MODE>
__global__ __launch_bounds__(256, 2)
void gemm4_kernel(const unsigned short* __restrict__ A,
                  const unsigned short* __restrict__ Wt,
                  const float* __restrict__ bias, void* __restrict__ dst,
                  const int* __restrict__ offs, const int* __restrict__ table,
                  const int* __restrict__ perm,
                  int K, int N, int ldd, int Btot, int GX, TP tpa, TP tpb)
{
    __shared__ unsigned short lds[2][2][BM * BK];   // 32 KB total

    const int bx = blockIdx.x;
    const int tid = threadIdx.x;

    if (bx >= GX) {
        // ---------- transpose role ----------
        int tile = (bx - GX) * gridDim.y + blockIdx.y;
        const float* src; unsigned short* dstp; int tK, tN;
        if (tile < tpa.ntiles) { src = tpa.src; dstp = tpa.dst; tK = tpa.K; tN = tpa.N; }
        else {
            tile -= tpa.ntiles;
            if (tile >= tpb.ntiles) return;
            src = tpb.src; dstp = tpb.dst; tK = tpb.K; tN = tpb.N;
        }
        int tk = tK >> 6, tn = tN >> 6;
        int z = tile / (tk * tn);
        int r = tile % (tk * tn);
        int k0 = (r % tk) * 64, n0 = (r / tk) * 64;
        const size_t toff = (size_t)z * tK * tN;
        const float* Ws = src + toff;
        unsigned short* Wd = dstp + toff;
        unsigned short* Tt = &lds[0][0][0];
        const int n = tid & 63;
        const int kq = tid >> 6;
        #pragma unroll
        for (int i = 0; i < 4; ++i) {
            int kk = kq * 16 + i * 4;
            const float* p = Ws + (size_t)(k0 + kk) * tN + n0 + n;
            float v0 = p[0];
            float v1 = p[(size_t)tN];
            float v2 = p[(size_t)2 * tN];
            float v3 = p[(size_t)3 * tN];
            unsigned int lo = (unsigned int)f32_to_bf16(v0) | ((unsigned int)f32_to_bf16(v1) << 16);
            unsigned int hi = (unsigned int)f32_to_bf16(v2) | ((unsigned int)f32_to_bf16(v3) << 16);
            int c = (kk >> 2) ^ (n & 15);
            *reinterpret_cast<uint2*>(Tt + n * 64 + c * 4) = make_uint2(lo, hi);
        }
        __syncthreads();
        #pragma unroll
        for (int it = 0; it < 2; ++it) {
            int c  = it * 256 + tid;
            int nn = c >> 3;
            int cg = c & 7;
            int c1 = (cg * 2) ^ (nn & 15);
            int c2 = (cg * 2 + 1) ^ (nn & 15);
            uint2 a = *reinterpret_cast<const uint2*>(Tt + nn * 64 + c1 * 4);
            uint2 b = *reinterpret_cast<const uint2*>(Tt + nn * 64 + c2 * 4);
            uint4 o = make_uint4(a.x, a.y, b.x, b.y);
            *reinterpret_cast<uint4*>(Wd + (size_t)(n0 + nn) * tK + k0 + cg * 8) = o;
        }
        return;
    }

    // ---------- GEMM role ----------
    int t, mtile, off, cnt;
    if (table != nullptr) {
        int v = table[bx];
        if (v < 0) return;
        t = v >> 16; mtile = v & 0xFFFF;
        off = offs[t]; cnt = offs[t + 1] - off;
    } else {
        t = 0; mtile = bx; off = 0; cnt = Btot;
    }
    const int n0 = blockIdx.y * BN;

    const int lane = tid & 63;
    const int wave = tid >> 6;
    const int wr = wave >> 1, wc = wave & 1;

    // staging geometry: lane -> row (lane>>2) within a 16-row line, 16B chunk (lane&3),
    // source chunk XOR (row&3). LDS dest stays linear (lane*16B per line).
    const int rl   = lane >> 2;                 // 0..15
    const int csrc = ((lane & 3) ^ (rl & 3)) * 8;
    const unsigned short* Ab = A + ((size_t)(off + mtile * BM + rl)) * K + csrc;
    const unsigned short* Bb = Wt + ((size_t)t * N + n0 + rl) * K + csrc;

    auto stage = [&](int buf, int k0) {
        #pragma unroll
        for (int jj = 0; jj < 2; ++jj) {
            int j = wave * 2 + jj;              // 0..7: 16-row line
            GLOAD_LDS16(Ab + (size_t)(j * 16) * K + k0, &lds[buf][0][j * 512]);
            GLOAD_LDS16(Bb + (size_t)(j * 16) * K + k0, &lds[buf][1][j * 512]);
        }
    };

    f32x4 acc[4][4];
    #pragma unroll
    for (int m = 0; m < 4; ++m)
        #pragma unroll
        for (int n = 0; n < 4; ++n)
            acc[m][n] = (f32x4){0.f, 0.f, 0.f, 0.f};

    auto compute = [&](int buf) {
        bf16x8 af[4], bfr[4];
        #pragma unroll
        for (int m = 0; m < 4; ++m) {
            int rf = wr * 64 + m * 16 + (lane & 15);
            af[m] = *reinterpret_cast<const bf16x8*>(
                &lds[buf][0][rf * 32 + (((lane >> 4) ^ (rf & 3)) * 8)]);
        }
        #pragma unroll
        for (int n = 0; n < 4; ++n) {
            int nf = wc * 64 + n * 16 + (lane & 15);
            bfr[n] = *reinterpret_cast<const bf16x8*>(
                &lds[buf][1][nf * 32 + (((lane >> 4) ^ (nf & 3)) * 8)]);
        }
        #pragma unroll
        for (int m = 0; m < 4; ++m)
            #pragma unroll
            for (int n = 0; n < 4; ++n)
                acc[m][n] = __builtin_amdgcn_mfma_f32_16x16x32_bf16(af[m], bfr[n], acc[m][n], 0, 0, 0);
    };

    const int nsteps = K / BK;
    stage(0, 0);
    __syncthreads();
    int cur = 0;
    for (int s = 0; s < nsteps; ++s) {
        if (s + 1 < nsteps) stage(cur ^ 1, (s + 1) * BK);   // issue-early: hides under compute
        compute(cur);
        __syncthreads();                                    // drains stage(next) + frag reads
        cur ^= 1;
    }

    // ---- epilogue ----
    const float* bt = bias + (size_t)t * N;
    #pragma unroll
    for (int n = 0; n < 4; ++n) {
        int col = n0 + wc * 64 + n * 16 + (lane & 15);
        float bv = bt[col];
        #pragma unroll
        for (int m = 0; m < 4; ++m) {
            int rbase = mtile * BM + wr * 64 + m * 16 + ((lane >> 4) << 2);
            #pragma unroll
            for (int j = 0; j < 4; ++j) {
                int local = rbase + j;
                if (local >= cnt) continue;
                float v = acc[m][n][j] + bv;
                if (MODE == 0) {
                    ((unsigned short*)dst)[(size_t)(off + local) * ldd + col] =
                        f32_to_bf16(fmaxf(v, 0.f));
                } else if (MODE == 1) {
                    ((float*)dst)[(size_t)(off + local) * ldd + col] = v;
                } else {
                    int grow = perm[off + local];
                    ((float*)dst)[(size_t)grow * ldd + col] = 1.f / (1.f + __expf(-v));
                }
            }
        }
    }
}

extern "C" void kernel_launch(void* const* d_in, const int* in_sizes, int n_in,
                              void* d_out, int out_size, void* d_ws, size_t ws_size,
                              hipStream_t stream) {
    const float* x      = (const float*)d_in[0];
    const int*   task   = (const int*)d_in[1];
    const float* eps    = (const float*)d_in[2];
    const float* enc_W1 = (const float*)d_in[3];
    const float* enc_b1 = (const float*)d_in[4];
    const float* enc_W2 = (const float*)d_in[5];
    const float* enc_b2 = (const float*)d_in[6];
    const float* enc_W3 = (const float*)d_in[7];
    const float* enc_b3 = (const float*)d_in[8];
    const float* enc_W4 = (const float*)d_in[9];
    const float* enc_b4 = (const float*)d_in[10];
    const float* ds_W1  = (const float*)d_in[11];
    const float* ds_b1  = (const float*)d_in[12];
    const float* ds_W2  = (const float*)d_in[13];
    const float* ds_b2  = (const float*)d_in[14];
    const float* hd_W1  = (const float*)d_in[15];
    const float* hd_b1  = (const float*)d_in[16];
    const float* hd_W2  = (const float*)d_in[17];
    const float* hd_b2  = (const float*)d_in[18];
    float* out = (float*)d_out;

    // ---- workspace layout ----
    char* ws = (char*)d_ws;
    int* perm  = (int*)ws;
    int* offs  = (int*)(ws + 16384);
    int* table = (int*)(ws + 16384 + 256);
    char* p = ws + 32768;
    unsigned short* xp = (unsigned short*)p; p += (size_t)PADROWS * 1024 * 2;
    unsigned short* h1 = (unsigned short*)p; p += (size_t)PADROWS * 2048 * 2;
    unsigned short* h2 = (unsigned short*)p; p += (size_t)PADROWS * 2048 * 2;
    unsigned short* zb = (unsigned short*)p; p += (size_t)PADROWS * 256 * 2;
    unsigned short* tw1  = (unsigned short*)p; p += (size_t)8 * 2048 * 1024 * 2;
    unsigned short* tw2  = (unsigned short*)p; p += (size_t)8 * 2048 * 2048 * 2;
    unsigned short* tw3  = (unsigned short*)p; p += (size_t)8 * 2048 * 2048 * 2;
    unsigned short* tw4  = (unsigned short*)p; p += (size_t)8 * 512 * 2048 * 2;
    unsigned short* tds1 = (unsigned short*)p; p += (size_t)2048 * 256 * 2;
    unsigned short* tds2 = (unsigned short*)p; p += (size_t)2048 * 2048 * 2;
    unsigned short* thd1 = (unsigned short*)p; p += (size_t)8 * 2048 * 2048 * 2;
    unsigned short* thd2 = (unsigned short*)p; p += (size_t)8 * 1024 * 2048 * 2;
    float* scat = out;   // reuse d_out as 8 MB scat scratch; fully overwritten later

    const TP tnone = { nullptr, nullptr, 64, 64, 0 };
    const TP tpW2  = { enc_W2, tw2, 2048, 2048, 8192 };
    const TP tpW3  = { enc_W3, tw3, 2048, 2048, 8192 };
    const TP tpW4  = { enc_W4, tw4, 2048,  512, 2048 };
    const TP tpDS1 = { ds_W1, tds1,  256, 2048,  128 };
    const TP tpDS2 = { ds_W2, tds2, 2048, 2048, 1024 };
    const TP tpHD1 = { hd_W1, thd1, 2048, 2048, 8192 };
    const TP tpHD2 = { hd_W2, thd2, 2048, 1024, 4096 };

    setup_kernel<<<1, 1024, 0, stream>>>(task, perm, offs, table);
    permute_cast_kernel<<<B_ROWS, 256, 0, stream>>>(x, perm, xp);

    // enc_W1 must be ready before the first GEMM -> standalone transpose
    transpose_cast_kernel<<<dim3(16, 32, 8), 256, 0, stream>>>(enc_W1, tw1, 1024, 2048);

    // D1: enc1 GEMM + transpose enc_W2   (8192 tiles / y16 = 512 extra x)
    gemm4_kernel<0><<<dim3(MAXTILES + 512, 16), 256, 0, stream>>>(xp, tw1, enc_b1, h1, offs, table, nullptr, 1024, 2048, 2048, B_ROWS, MAXTILES, tpW2, tnone);
    // D2: enc2 GEMM + transpose enc_W3
    gemm4_kernel<0><<<dim3(MAXTILES + 512, 16), 256, 0, stream>>>(h1, tw2, enc_b2, h2, offs, table, nullptr, 2048, 2048, 2048, B_ROWS, MAXTILES, tpW3, tnone);
    // D3: enc3 GEMM + transpose enc_W4 + ds_W1   ((2048+128)/16 = 136 extra x)
    gemm4_kernel<0><<<dim3(MAXTILES + 136, 16), 256, 0, stream>>>(h2, tw3, enc_b3, h1, offs, table, nullptr, 2048, 2048, 2048, B_ROWS, MAXTILES, tpW4, tpDS1);
    // D4: enc4 GEMM (y=4) + transpose ds_W2   (1024/4 = 256 extra x)
    gemm4_kernel<1><<<dim3(MAXTILES + 256, 4), 256, 0, stream>>>(h1, tw4, enc_b4, scat, offs, table, nullptr, 2048, 512, 512, B_ROWS, MAXTILES, tpDS2, tnone);

    vae_kernel<<<B_ROWS, 256, 0, stream>>>(scat, eps, perm, zb);

    // D5: ds1 GEMM (ungrouped, GX=32) + transpose hd_W1   (8192/16 = 512 extra x)
    gemm4_kernel<0><<<dim3(32 + 512, 16), 256, 0, stream>>>(zb, tds1, ds_b1, h2, nullptr, nullptr, nullptr, 256, 2048, 2048, B_ROWS, 32, tpHD1, tnone);
    // D6: ds2 GEMM (ungrouped) + transpose hd_W2   (4096/16 = 256 extra x)
    gemm4_kernel<0><<<dim3(32 + 256, 16), 256, 0, stream>>>(h2, tds2, ds_b2, h1, nullptr, nullptr, nullptr, 2048, 2048, 2048, B_ROWS, 32, tpHD2, tnone);

    // D7: hd1 GEMM (grouped, pure)
    gemm4_kernel<0><<<dim3(MAXTILES, 16), 256, 0, stream>>>(h1, thd1, hd_b1, h2, offs, table, nullptr, 2048, 2048, 2048, B_ROWS, MAXTILES, tnone, tnone);
    // D8: hd2 GEMM (grouped, sigmoid scatter, y=8)
    gemm4_kernel<2><<<dim3(MAXTILES, 8), 256, 0, stream>>>(h2, thd2, hd_b2, out, offs, table, perm, 2048, 1024, 1024, B_ROWS, MAXTILES, tnone, tnone);
}